// Round 1
// baseline (156.297 us; speedup 1.0000x reference)
//
#include <hip/hip_runtime.h>

#define SEQ_LEN   512
#define PRED_LEN  96
#define PATCH_LEN 16
#define STRIDE    8
#define NUM_LAYERS 3
#define NQ        4
#define NUM_PATCHES 63
#define BB        32
#define MM        128
#define NROWS     (BB*MM)            // 4096
#define FAN_IN    (NUM_PATCHES*NQ)   // 252

// ---------------- kernel 0: precompute the 12 Rot unitaries ----------------
// Rot(phi,theta,omega) = RZ(omega) RY(theta) RZ(phi):
// m00 =  e^{-i(phi+omega)/2} cos(t/2)   m01 = -e^{+i(phi-omega)/2} sin(t/2)
// m10 =  e^{-i(phi-omega)/2} sin(t/2)   m11 =  e^{+i(phi+omega)/2} cos(t/2)
__global__ void gates_kernel(const float* __restrict__ w, float* __restrict__ gates) {
    int g = threadIdx.x;
    if (g >= NUM_LAYERS * NQ) return;
    float phi = w[g*3+0], theta = w[g*3+1], omega = w[g*3+2];
    float ct = cosf(0.5f*theta), st = sinf(0.5f*theta);
    float ap = 0.5f*(phi+omega), am = 0.5f*(phi-omega);
    float cap = cosf(ap), sap = sinf(ap);
    float cam = cosf(am), sam = sinf(am);
    float* o = gates + g*8;
    o[0] =  cap*ct; o[1] = -sap*ct;   // m00
    o[2] = -cam*st; o[3] = -sam*st;   // m01
    o[4] =  cam*st; o[5] = -sam*st;   // m10
    o[6] =  cap*ct; o[7] =  sap*ct;   // m11
}

// ---------------- kernel 1: statevector sim, one thread per patch ----------------
#define APPLY_ROT(g, bm) {                                                    \
    const float m00r=sg[(g)*8+0], m00i=sg[(g)*8+1];                           \
    const float m01r=sg[(g)*8+2], m01i=sg[(g)*8+3];                           \
    const float m10r=sg[(g)*8+4], m10i=sg[(g)*8+5];                           \
    const float m11r=sg[(g)*8+6], m11i=sg[(g)*8+7];                           \
    _Pragma("unroll")                                                         \
    for (int i = 0; i < 16; ++i) {                                            \
        if (i & (bm)) continue;                                               \
        int j = i | (bm);                                                     \
        float s0r=re[i], s0i=im[i], s1r=re[j], s1i=im[j];                     \
        re[i] = m00r*s0r - m00i*s0i + m01r*s1r - m01i*s1i;                    \
        im[i] = m00r*s0i + m00i*s0r + m01r*s1i + m01i*s1r;                    \
        re[j] = m10r*s0r - m10i*s0i + m11r*s1r - m11i*s1i;                    \
        im[j] = m10r*s0i + m10i*s0r + m11r*s1i + m11i*s1r;                    \
    } }

#define CNOT(cm, tm) {                                                        \
    _Pragma("unroll")                                                         \
    for (int i = 0; i < 16; ++i) {                                            \
        if ((i & (cm)) && !(i & (tm))) {                                      \
            int j = i | (tm);                                                 \
            float tr = re[i]; re[i]=re[j]; re[j]=tr;                          \
            float ti = im[i]; im[i]=im[j]; im[j]=ti;                          \
        }                                                                     \
    } }

__global__ __launch_bounds__(256) void qml_kernel(const float* __restrict__ x,
                                                  const float* __restrict__ gates,
                                                  float* __restrict__ enc_t) {
    __shared__ float sg[96];
    if (threadIdx.x < 96) sg[threadIdx.x] = gates[threadIdx.x];
    __syncthreads();

    const int p   = blockIdx.x;                       // patch 0..62
    const int row = blockIdx.y * 256 + threadIdx.x;   // 0..4095  (b*128+m)
    const int b   = row >> 7;
    const int m   = row & 127;
    const float* xp = x + b * (SEQ_LEN * MM) + m;     // x[b, :, m], stride MM

    float re[16], im[16];
    float nrm = 0.f;
    const int col0 = p * STRIDE;
    #pragma unroll
    for (int k = 0; k < 16; ++k) {
        float v = xp[(col0 + k) * MM] + 1e-6f;
        re[k] = v;
        im[k] = 0.f;
        nrm = fmaf(v, v, nrm);
    }
    const float inv = rsqrtf(nrm);
    #pragma unroll
    for (int k = 0; k < 16; ++k) re[k] *= inv;

    // layer 0: Rot on wires 0..3 (gates 0..3), r=1 -> CNOT (0,1)(1,2)(2,3)(3,0)
    APPLY_ROT(0, 8) APPLY_ROT(1, 4) APPLY_ROT(2, 2) APPLY_ROT(3, 1)
    CNOT(8, 4) CNOT(4, 2) CNOT(2, 1) CNOT(1, 8)
    // layer 1: gates 4..7, r=2 -> CNOT (0,2)(1,3)(2,0)(3,1)
    APPLY_ROT(4, 8) APPLY_ROT(5, 4) APPLY_ROT(6, 2) APPLY_ROT(7, 1)
    CNOT(8, 2) CNOT(4, 1) CNOT(2, 8) CNOT(1, 4)
    // layer 2: gates 8..11, r=3 -> CNOT (0,3)(1,0)(2,1)(3,2)
    APPLY_ROT(8, 8) APPLY_ROT(9, 4) APPLY_ROT(10, 2) APPLY_ROT(11, 1)
    CNOT(8, 1) CNOT(4, 8) CNOT(2, 4) CNOT(1, 2)

    float z0 = 0.f, z1 = 0.f, z2 = 0.f, z3 = 0.f;
    #pragma unroll
    for (int i = 0; i < 16; ++i) {
        float pr = re[i]*re[i] + im[i]*im[i];
        z0 += (i & 8) ? -pr : pr;
        z1 += (i & 4) ? -pr : pr;
        z2 += (i & 2) ? -pr : pr;
        z3 += (i & 1) ? -pr : pr;
    }
    // enc_t[j][row], j = p*4 + wire  -> coalesced over row
    float* e = enc_t + p * 4 * NROWS + row;
    e[0*NROWS] = z0;
    e[1*NROWS] = z1;
    e[2*NROWS] = z2;
    e[3*NROWS] = z3;
}

// ---------------- kernel 2: fused head + skip GEMM ----------------
#define TT 8
__global__ __launch_bounds__(128) void head_kernel(const float* __restrict__ x,
                                                   const float* __restrict__ enc_t,
                                                   const float* __restrict__ head_w,
                                                   const float* __restrict__ head_b,
                                                   const float* __restrict__ skip_w,
                                                   const float* __restrict__ skip_b,
                                                   float* __restrict__ out) {
    const int m  = threadIdx.x;          // 0..127
    const int b  = blockIdx.y;           // 0..31
    const int t0 = blockIdx.x * TT;      // 0,8,...,88
    const int row = b * MM + m;

    float acc[TT];
    #pragma unroll
    for (int tt = 0; tt < TT; ++tt) acc[tt] = head_b[t0+tt] + skip_b[t0+tt];

    const float* e = enc_t + row;
    #pragma unroll 4
    for (int j = 0; j < FAN_IN; ++j) {
        float ev = e[j * NROWS];
        #pragma unroll
        for (int tt = 0; tt < TT; ++tt)
            acc[tt] = fmaf(ev, head_w[(t0+tt)*FAN_IN + j], acc[tt]);
    }

    const float* xr = x + b * (SEQ_LEN * MM) + m;
    #pragma unroll 4
    for (int l = 0; l < SEQ_LEN; ++l) {
        float xv = xr[l * MM];
        #pragma unroll
        for (int tt = 0; tt < TT; ++tt)
            acc[tt] = fmaf(xv, skip_w[(t0+tt)*SEQ_LEN + l], acc[tt]);
    }

    float* o = out + b * (PRED_LEN * MM) + t0 * MM + m;
    #pragma unroll
    for (int tt = 0; tt < TT; ++tt) o[tt * MM] = acc[tt];
}

extern "C" void kernel_launch(void* const* d_in, const int* in_sizes, int n_in,
                              void* d_out, int out_size, void* d_ws, size_t ws_size,
                              hipStream_t stream) {
    const float* x       = (const float*)d_in[0];
    const float* weights = (const float*)d_in[1];
    const float* head_w  = (const float*)d_in[2];
    const float* head_b  = (const float*)d_in[3];
    const float* skip_w  = (const float*)d_in[4];
    const float* skip_b  = (const float*)d_in[5];
    float* out = (float*)d_out;

    float* gates = (float*)d_ws;              // 96 floats
    float* enc_t = (float*)d_ws + 256;        // 252*4096 floats = 4.13 MB

    hipLaunchKernelGGL(gates_kernel, dim3(1), dim3(16), 0, stream, weights, gates);
    hipLaunchKernelGGL(qml_kernel, dim3(NUM_PATCHES, NROWS/256), dim3(256), 0, stream,
                       x, gates, enc_t);
    hipLaunchKernelGGL(head_kernel, dim3(PRED_LEN/TT, BB), dim3(128), 0, stream,
                       x, enc_t, head_w, head_b, skip_w, skip_b, out);
}

// Round 2
// 140.550 us; speedup vs baseline: 1.1120x; 1.1120x over previous
//
#include <hip/hip_runtime.h>

#define SEQ_LEN   512
#define PRED_LEN  96
#define PATCH_LEN 16
#define STRIDE    8
#define NUM_LAYERS 3
#define NQ        4
#define NUM_PATCHES 63
#define BB        32
#define MM        128
#define NROWS     (BB*MM)            // 4096
#define FAN_IN    (NUM_PATCHES*NQ)   // 252

// ---------------- kernel 1: statevector sim, one thread per patch ----------------
// Gates computed in-block (threads 0..11) from weights:
// Rot(phi,theta,omega) = RZ(omega) RY(theta) RZ(phi)
#define APPLY_ROT(g, bm) {                                                    \
    const float m00r=sg[(g)*8+0], m00i=sg[(g)*8+1];                           \
    const float m01r=sg[(g)*8+2], m01i=sg[(g)*8+3];                           \
    const float m10r=sg[(g)*8+4], m10i=sg[(g)*8+5];                           \
    const float m11r=sg[(g)*8+6], m11i=sg[(g)*8+7];                           \
    _Pragma("unroll")                                                         \
    for (int i = 0; i < 16; ++i) {                                            \
        if (i & (bm)) continue;                                               \
        int j = i | (bm);                                                     \
        float s0r=re[i], s0i=im[i], s1r=re[j], s1i=im[j];                     \
        re[i] = m00r*s0r - m00i*s0i + m01r*s1r - m01i*s1i;                    \
        im[i] = m00r*s0i + m00i*s0r + m01r*s1i + m01i*s1r;                    \
        re[j] = m10r*s0r - m10i*s0i + m11r*s1r - m11i*s1i;                    \
        im[j] = m10r*s0i + m10i*s0r + m11r*s1i + m11i*s1r;                    \
    } }

#define CNOT(cm, tm) {                                                        \
    _Pragma("unroll")                                                         \
    for (int i = 0; i < 16; ++i) {                                            \
        if ((i & (cm)) && !(i & (tm))) {                                      \
            int j = i | (tm);                                                 \
            float tr = re[i]; re[i]=re[j]; re[j]=tr;                          \
            float ti = im[i]; im[i]=im[j]; im[j]=ti;                          \
        }                                                                     \
    } }

__global__ __launch_bounds__(256) void qml_kernel(const float* __restrict__ x,
                                                  const float* __restrict__ w,
                                                  float* __restrict__ enc_t) {
    __shared__ float sg[96];
    if (threadIdx.x < NUM_LAYERS * NQ) {
        int g = threadIdx.x;
        float phi = w[g*3+0], theta = w[g*3+1], omega = w[g*3+2];
        float ct = cosf(0.5f*theta), st = sinf(0.5f*theta);
        float ap = 0.5f*(phi+omega), am = 0.5f*(phi-omega);
        float cap = cosf(ap), sap = sinf(ap);
        float cam = cosf(am), sam = sinf(am);
        float* o = sg + g*8;
        o[0] =  cap*ct; o[1] = -sap*ct;   // m00
        o[2] = -cam*st; o[3] = -sam*st;   // m01
        o[4] =  cam*st; o[5] = -sam*st;   // m10
        o[6] =  cap*ct; o[7] =  sap*ct;   // m11
    }
    __syncthreads();

    const int p   = blockIdx.x;                       // patch 0..62
    const int row = blockIdx.y * 256 + threadIdx.x;   // 0..4095  (b*128+m)
    const int b   = row >> 7;
    const int m   = row & 127;
    const float* xp = x + b * (SEQ_LEN * MM) + m;     // x[b, :, m], stride MM

    float re[16], im[16];
    float nrm = 0.f;
    const int col0 = p * STRIDE;
    #pragma unroll
    for (int k = 0; k < 16; ++k) {
        float v = xp[(col0 + k) * MM] + 1e-6f;
        re[k] = v;
        im[k] = 0.f;
        nrm = fmaf(v, v, nrm);
    }
    const float inv = rsqrtf(nrm);
    #pragma unroll
    for (int k = 0; k < 16; ++k) re[k] *= inv;

    // layer 0: gates 0..3, r=1 -> CNOT (0,1)(1,2)(2,3)(3,0)
    APPLY_ROT(0, 8) APPLY_ROT(1, 4) APPLY_ROT(2, 2) APPLY_ROT(3, 1)
    CNOT(8, 4) CNOT(4, 2) CNOT(2, 1) CNOT(1, 8)
    // layer 1: gates 4..7, r=2 -> CNOT (0,2)(1,3)(2,0)(3,1)
    APPLY_ROT(4, 8) APPLY_ROT(5, 4) APPLY_ROT(6, 2) APPLY_ROT(7, 1)
    CNOT(8, 2) CNOT(4, 1) CNOT(2, 8) CNOT(1, 4)
    // layer 2: gates 8..11, r=3 -> CNOT (0,3)(1,0)(2,1)(3,2)
    APPLY_ROT(8, 8) APPLY_ROT(9, 4) APPLY_ROT(10, 2) APPLY_ROT(11, 1)
    CNOT(8, 1) CNOT(4, 8) CNOT(2, 4) CNOT(1, 2)

    float z0 = 0.f, z1 = 0.f, z2 = 0.f, z3 = 0.f;
    #pragma unroll
    for (int i = 0; i < 16; ++i) {
        float pr = re[i]*re[i] + im[i]*im[i];
        z0 += (i & 8) ? -pr : pr;
        z1 += (i & 4) ? -pr : pr;
        z2 += (i & 2) ? -pr : pr;
        z3 += (i & 1) ? -pr : pr;
    }
    // enc_t[j][row], j = p*4 + wire  -> coalesced over row
    float* e = enc_t + p * 4 * NROWS + row;
    e[0*NROWS] = z0;
    e[1*NROWS] = z1;
    e[2*NROWS] = z2;
    e[3*NROWS] = z3;
}

// ---------------- kernel 2: fused head + skip GEMM ----------------
// block = 512 threads: (m 0..127) x (ks 0..3, K-split inside block)
// grid  = 256 blocks: 8 t-tiles (TT=12) x 32 b, XCD-chunk swizzled
#define TT 12
#define NTILE 8
__global__ __launch_bounds__(512) void head_kernel(const float* __restrict__ x,
                                                   const float* __restrict__ enc_t,
                                                   const float* __restrict__ head_w,
                                                   const float* __restrict__ head_b,
                                                   const float* __restrict__ skip_w,
                                                   const float* __restrict__ skip_b,
                                                   float* __restrict__ out) {
    const int tid = threadIdx.x;
    const int m   = tid & 127;
    const int ks  = tid >> 7;            // 0..3

    // XCD-chunked bijective swizzle: launch id L -> XCD L%8; give XCD k
    // logical tiles [k*32, k*32+32) so all 8 t-tiles of a b share an XCD.
    const int L = blockIdx.x;            // 0..255
    const int T = (L & 7) * 32 + (L >> 3);
    const int b    = T >> 3;             // 0..31
    const int tile = T & 7;              // 0..7
    const int t0   = tile * TT;
    const int row  = b * MM + m;

    float acc[TT];
    #pragma unroll
    for (int tt = 0; tt < TT; ++tt) acc[tt] = 0.f;

    // enc part: 252 = 4*63
    const float* e = enc_t + row;
    {
        const int j0 = ks * 63;
        #pragma unroll 3
        for (int j = j0; j < j0 + 63; ++j) {
            float ev = e[j * NROWS];
            #pragma unroll
            for (int tt = 0; tt < TT; ++tt)
                acc[tt] = fmaf(ev, head_w[(t0+tt)*FAN_IN + j], acc[tt]);
        }
    }
    // skip part: 512 = 4*128
    {
        const float* xr = x + b * (SEQ_LEN * MM) + m;
        const int l0 = ks * 128;
        #pragma unroll 4
        for (int l = l0; l < l0 + 128; ++l) {
            float xv = xr[l * MM];
            #pragma unroll
            for (int tt = 0; tt < TT; ++tt)
                acc[tt] = fmaf(xv, skip_w[(t0+tt)*SEQ_LEN + l], acc[tt]);
        }
    }

    __shared__ float red[TT][512];
    #pragma unroll
    for (int tt = 0; tt < TT; ++tt) red[tt][tid] = acc[tt];
    __syncthreads();

    if (tid < 128) {
        float* o = out + b * (PRED_LEN * MM) + t0 * MM + m;
        #pragma unroll
        for (int tt = 0; tt < TT; ++tt) {
            float s = red[tt][m] + red[tt][m+128] + red[tt][m+256] + red[tt][m+384];
            o[tt * MM] = s + head_b[t0+tt] + skip_b[t0+tt];
        }
    }
}

extern "C" void kernel_launch(void* const* d_in, const int* in_sizes, int n_in,
                              void* d_out, int out_size, void* d_ws, size_t ws_size,
                              hipStream_t stream) {
    const float* x       = (const float*)d_in[0];
    const float* weights = (const float*)d_in[1];
    const float* head_w  = (const float*)d_in[2];
    const float* head_b  = (const float*)d_in[3];
    const float* skip_w  = (const float*)d_in[4];
    const float* skip_b  = (const float*)d_in[5];
    float* out = (float*)d_out;

    float* enc_t = (float*)d_ws;              // 252*4096 floats = 4.13 MB

    hipLaunchKernelGGL(qml_kernel, dim3(NUM_PATCHES, NROWS/256), dim3(256), 0, stream,
                       x, weights, enc_t);
    hipLaunchKernelGGL(head_kernel, dim3(NTILE*BB), dim3(512), 0, stream,
                       x, enc_t, head_w, head_b, skip_w, skip_b, out);
}

// Round 3
// 124.145 us; speedup vs baseline: 1.2590x; 1.1321x over previous
//
#include <hip/hip_runtime.h>

#define SEQ_LEN   512
#define PRED_LEN  96
#define PATCH_LEN 16
#define STRIDE    8
#define NQ        4
#define NUM_PATCHES 63
#define BB        32
#define MM        128
#define NROWS     (BB*MM)            // 4096
#define FAN_IN    (NUM_PATCHES*NQ)   // 252

// ---------------- kernel 0: build the full 16x16 circuit unitary ----------------
// U = product of all gates in application order. One block, 128 threads =
// (pair 0..7) x (col 0..15). Output layout (column-major, for scalar loads):
//   u[k*32 + i]      = Re U[i][k]
//   u[k*32 + 16 + i] = Im U[i][k]
__global__ __launch_bounds__(128) void build_u_kernel(const float* __restrict__ w,
                                                      float* __restrict__ u) {
    __shared__ float Ur[16][17], Ui[16][17];
    const int tid = threadIdx.x;
    const int col = tid & 15;
    const int pr  = tid >> 4;        // pair index 0..7

    // init U = I
    for (int idx = tid; idx < 256; idx += 128) {
        int i = idx >> 4, j = idx & 15;
        Ur[i][j] = (i == j) ? 1.f : 0.f;
        Ui[i][j] = 0.f;
    }

    for (int l = 0; l < 3; ++l) {
        for (int wi = 0; wi < 4; ++wi) {
            const float* g = w + (l*4 + wi)*3;
            float phi = g[0], th = g[1], om = g[2];
            float ct = cosf(0.5f*th), st = sinf(0.5f*th);
            float ap = 0.5f*(phi+om), am = 0.5f*(phi-om);
            float m00r =  cosf(ap)*ct, m00i = -sinf(ap)*ct;
            float m01r = -cosf(am)*st, m01i = -sinf(am)*st;
            float m10r =  cosf(am)*st, m10i = -sinf(am)*st;
            float m11r =  cosf(ap)*ct, m11i =  sinf(ap)*ct;
            int bp = 3 - wi;                                  // wire wi <-> bit 3-wi
            int i0 = ((pr >> bp) << (bp+1)) | (pr & ((1<<bp)-1));
            int i1 = i0 | (1 << bp);
            __syncthreads();
            float a_r = Ur[i0][col], a_i = Ui[i0][col];
            float b_r = Ur[i1][col], b_i = Ui[i1][col];
            // thread owns rows (i0,i1) of its column exclusively -> no barrier needed
            Ur[i0][col] = m00r*a_r - m00i*a_i + m01r*b_r - m01i*b_i;
            Ui[i0][col] = m00r*a_i + m00i*a_r + m01r*b_i + m01i*b_r;
            Ur[i1][col] = m10r*a_r - m10i*a_i + m11r*b_r - m11i*b_i;
            Ui[i1][col] = m10r*a_i + m10i*a_r + m11r*b_i + m11i*b_r;
        }
        int r = (l % 3) + 1;                                  // ranges: 1,2,3
        for (int wi = 0; wi < 4; ++wi) {
            int cm = 8 >> wi, tm = 8 >> ((wi + r) & 3);
            __syncthreads();
            if (pr < 4) {
                // enumerate the 4 rows with control set, target clear
                int i = cm, prr = pr;
                int rem = 15 & ~cm & ~tm;                     // the two free bits
                for (int bpos = 0; bpos < 4; ++bpos)
                    if (rem & (1 << bpos)) { if (prr & 1) i |= (1 << bpos); prr >>= 1; }
                int j = i | tm;
                float tr = Ur[i][col], ti = Ui[i][col];
                Ur[i][col] = Ur[j][col]; Ui[i][col] = Ui[j][col];
                Ur[j][col] = tr;         Ui[j][col] = ti;
            }
        }
    }
    __syncthreads();
    for (int idx = tid; idx < 256; idx += 128) {
        int k = idx >> 4, i = idx & 15;
        u[k*32 + i]      = Ur[i][k];
        u[k*32 + 16 + i] = Ui[i][k];
    }
}

// ---------------- kernel 1: encode = U matvec + PauliZ, one thread per patch ----------------
__global__ __launch_bounds__(256) void encode_kernel(const float* __restrict__ x,
                                                     const float* __restrict__ u,
                                                     float* __restrict__ enc_t) {
    const int p   = blockIdx.x;                       // patch 0..62
    const int row = blockIdx.y * 256 + threadIdx.x;   // 0..4095  (b*128+m)
    const int b   = row >> 7;
    const int m   = row & 127;
    const float* xp = x + b * (SEQ_LEN * MM) + p * STRIDE * MM + m;

    float yr[16], yi[16];
    #pragma unroll
    for (int i = 0; i < 16; ++i) { yr[i] = 0.f; yi[i] = 0.f; }
    float tot = 0.f;
    #pragma unroll
    for (int k = 0; k < 16; ++k) {
        float v = xp[k * MM] + 1e-6f;
        tot = fmaf(v, v, tot);                         // ||v||^2 (= ||Uv||^2, U unitary)
        const float* uc = u + k * 32;                  // uniform -> s_load
        #pragma unroll
        for (int i = 0; i < 16; ++i) {
            yr[i] = fmaf(uc[i],      v, yr[i]);
            yi[i] = fmaf(uc[16 + i], v, yi[i]);
        }
    }
    float z0 = 0.f, z1 = 0.f, z2 = 0.f, z3 = 0.f;
    #pragma unroll
    for (int i = 0; i < 16; ++i) {
        float pr2 = yr[i]*yr[i] + yi[i]*yi[i];
        z0 += (i & 8) ? -pr2 : pr2;
        z1 += (i & 4) ? -pr2 : pr2;
        z2 += (i & 2) ? -pr2 : pr2;
        z3 += (i & 1) ? -pr2 : pr2;
    }
    const float invt = 1.0f / tot;
    float* e = enc_t + p * 4 * NROWS + row;            // enc_t[j][row], coalesced over row
    e[0*NROWS] = z0 * invt;
    e[1*NROWS] = z1 * invt;
    e[2*NROWS] = z2 * invt;
    e[3*NROWS] = z3 * invt;
}

// ---------------- kernel 2: fused head + skip GEMM ----------------
// block = 256 threads: (m 0..63) x (ks 0..3, K-split; ks wave-uniform via readfirstlane
// so weight loads stay SCALAR). grid = 512: 8 t-tiles x 32 b x 2 m-halves, XCD-chunked.
#define TT 12
__global__ __launch_bounds__(256) void head_kernel(const float* __restrict__ x,
                                                   const float* __restrict__ enc_t,
                                                   const float* __restrict__ head_w,
                                                   const float* __restrict__ head_b,
                                                   const float* __restrict__ skip_w,
                                                   const float* __restrict__ skip_b,
                                                   float* __restrict__ out) {
    const int tid = threadIdx.x;
    const int m   = tid & 63;
    const int ks  = __builtin_amdgcn_readfirstlane(tid >> 6);   // 0..3, wave-uniform

    // bijective XCD-chunk swizzle: XCD k gets 4 consecutive b's (all tiles/halves)
    const int L = blockIdx.x;                 // 0..511
    const int T = (L & 7) * 64 + (L >> 3);
    const int b    = T >> 4;                  // 0..31
    const int tile = (T >> 1) & 7;            // 0..7
    const int mh   = T & 1;                   // 0..1
    const int t0   = tile * TT;
    const int row  = b * MM + mh * 64 + m;

    float acc[TT];
    #pragma unroll
    for (int tt = 0; tt < TT; ++tt) acc[tt] = 0.f;

    // enc part: 252 = 4*63
    {
        const float* e = enc_t + row;
        const int j0 = ks * 63;
        #pragma unroll 3
        for (int j = j0; j < j0 + 63; ++j) {
            float ev = e[j * NROWS];
            #pragma unroll
            for (int tt = 0; tt < TT; ++tt)
                acc[tt] = fmaf(ev, head_w[(t0+tt)*FAN_IN + j], acc[tt]);
        }
    }
    // skip part: 512 = 4*128
    {
        const float* xr = x + b * (SEQ_LEN * MM) + mh * 64 + m;
        const int l0 = ks * 128;
        #pragma unroll 4
        for (int l = l0; l < l0 + 128; ++l) {
            float xv = xr[l * MM];
            #pragma unroll
            for (int tt = 0; tt < TT; ++tt)
                acc[tt] = fmaf(xv, skip_w[(t0+tt)*SEQ_LEN + l], acc[tt]);
        }
    }

    __shared__ float red[TT][256];
    #pragma unroll
    for (int tt = 0; tt < TT; ++tt) red[tt][tid] = acc[tt];
    __syncthreads();

    if (tid < 64) {
        float* o = out + b * (PRED_LEN * MM) + t0 * MM + mh * 64 + m;
        #pragma unroll
        for (int tt = 0; tt < TT; ++tt) {
            float s = red[tt][m] + red[tt][m+64] + red[tt][m+128] + red[tt][m+192];
            o[tt * MM] = s + head_b[t0+tt] + skip_b[t0+tt];
        }
    }
}

extern "C" void kernel_launch(void* const* d_in, const int* in_sizes, int n_in,
                              void* d_out, int out_size, void* d_ws, size_t ws_size,
                              hipStream_t stream) {
    const float* x       = (const float*)d_in[0];
    const float* weights = (const float*)d_in[1];
    const float* head_w  = (const float*)d_in[2];
    const float* head_b  = (const float*)d_in[3];
    const float* skip_w  = (const float*)d_in[4];
    const float* skip_b  = (const float*)d_in[5];
    float* out = (float*)d_out;

    float* u     = (float*)d_ws;              // 512 floats
    float* enc_t = (float*)d_ws + 1024;       // 252*4096 floats = 4.13 MB

    hipLaunchKernelGGL(build_u_kernel, dim3(1), dim3(128), 0, stream, weights, u);
    hipLaunchKernelGGL(encode_kernel, dim3(NUM_PATCHES, NROWS/256), dim3(256), 0, stream,
                       x, u, enc_t);
    hipLaunchKernelGGL(head_kernel, dim3(512), dim3(256), 0, stream,
                       x, enc_t, head_w, head_b, skip_w, skip_b, out);
}